// Round 2
// baseline (396.042 us; speedup 1.0000x reference)
//
#include <hip/hip_runtime.h>

typedef __attribute__((ext_vector_type(8))) __bf16 bf16x8;
typedef __attribute__((ext_vector_type(4))) __bf16 bf16x4;
typedef __attribute__((ext_vector_type(4))) float f32x4;

constexpr int kB = 8, kN = 8192, kE = 65536;
constexpr int kBN = kB * kN;    // 65536 nodes total
constexpr int kBE = kB * kE;    // 524288 edges total
constexpr int kDN = 64, kDE = 64, kIU = 128;

constexpr int XS = 200;  // X row stride in bf16 (192 + 8 pad) -> row shift 4 banks
constexpr int HS = 136;  // H row stride (128 + 8)
constexpr int ES = 72;   // E row stride (64 + 8)

// LDS-only barrier: all cross-wave traffic in this kernel flows through LDS,
// so we only need lgkmcnt(0) before s_barrier. This leaves gathers / stores /
// atomics outstanding across the barrier (vs __syncthreads' full vmcnt(0)
// drain -- the round-1 latency killer).
__device__ __forceinline__ void lds_barrier() {
    asm volatile("s_waitcnt lgkmcnt(0)\n\ts_barrier" ::: "memory");
}

__global__ __launch_bounds__(256, 3)
void edge_mlp_kernel(const float* __restrict__ nodes,
                     const float* __restrict__ edges,
                     const int* __restrict__ senders,
                     const int* __restrict__ receivers,
                     const float* __restrict__ W_in,
                     const float* __restrict__ b_in,
                     const float* __restrict__ W_out,
                     const float* __restrict__ b_out,
                     const float* __restrict__ W_edge,
                     const float* __restrict__ b_edge,
                     float* __restrict__ edges_out,
                     float* __restrict__ out_sf,
                     float* __restrict__ out_rf,
                     float* __restrict__ sums,
                     float* __restrict__ counts)
{
    __shared__ alignas(16) __bf16 Xs_[64 * XS];   // 25.6 KB
    __shared__ alignas(16) __bf16 Hs_[64 * HS];   // 17.4 KB
    __shared__ alignas(16) __bf16 Es_[64 * ES];   //  9.2 KB
    __shared__ int rsS[2][64];                    // double-buffered scatter idx

    const int tid  = threadIdx.x;
    const int lane = tid & 63;
    const int wave = tid >> 6;
    const int c16  = lane & 15;
    const int q    = lane >> 4;

    // ---- weight B-fragments in registers (loaded once) ----
    bf16x8 winf[6][2];
#pragma unroll
    for (int kk = 0; kk < 6; ++kk)
#pragma unroll
        for (int nt = 0; nt < 2; ++nt)
#pragma unroll
            for (int j = 0; j < 8; ++j)
                winf[kk][nt][j] =
                    (__bf16)W_in[(kk * 32 + q * 8 + j) * kIU + wave * 32 + nt * 16 + c16];

    bf16x8 woutf[4];
#pragma unroll
    for (int kk = 0; kk < 4; ++kk)
#pragma unroll
        for (int j = 0; j < 8; ++j)
            woutf[kk][j] =
                (__bf16)W_out[(kk * 32 + q * 8 + j) * kDN + wave * 16 + c16];

    bf16x8 wedgef[2];
#pragma unroll
    for (int kk = 0; kk < 2; ++kk)
#pragma unroll
        for (int j = 0; j < 8; ++j)
            wedgef[kk][j] =
                (__bf16)W_edge[(kk * 32 + q * 8 + j) * kDE + wave * 16 + c16];

    const float bin0 = b_in[wave * 32 + c16];
    const float bin1 = b_in[wave * 32 + 16 + c16];
    const float bo   = b_out[wave * 16 + c16];
    const float beg  = b_edge[wave * 16 + c16];

    const int row = tid >> 2;   // 0..63: edge row within tile
    const int qt  = tid & 3;    // column-quarter owner

    const int ntiles = kBE / 64;       // 8192
    const int stride = gridDim.x;

    // ---- prologue: idx(t), gathers(t), idx(t+stride) ----
    int t = blockIdx.x;
    int rV, sV;        // indices for current tile's row
    int rN, sN;        // indices for next tile's row
    float4 G[12];      // gathered rows for current tile
    {
        const int g = t * 64 + row;
        rV = receivers[g];
        sV = senders[g];
        const int b  = g >> 16;
        const int rg = (rV < 0) ? (kBN - 1) : rV + (b << 13);
        const int sg = (sV < 0) ? (kBN - 1) : sV + (b << 13);
        const float4* nrec = (const float4*)nodes + (size_t)rg * 16;
        const float4* ez   = (const float4*)edges + (size_t)g * 16;
        const float4* nsnd = (const float4*)nodes + (size_t)sg * 16;
#pragma unroll
        for (int i = 0; i < 4; ++i) {
            G[i]     = nrec[qt + 4 * i];
            G[4 + i] = ez  [qt + 4 * i];
            G[8 + i] = nsnd[qt + 4 * i];
        }
        const int t1 = (t + stride < ntiles) ? (t + stride) : t;
        const int g1 = t1 * 64 + row;
        rN = receivers[g1];
        sN = senders[g1];
    }

    int buf = 0;
    for (; t < ntiles; t += stride) {
        const int g0 = t * 64;

        // ---- stage X (bank-spread column map), rsS, per-edge side effects ----
        {
            const int b  = (g0 + row) >> 16;
            const int rs = (rV < 0) ? -1 : rV + (b << 13);
            if (qt == 0) {
                rsS[buf][row] = rs;
                const int g = g0 + row;
                out_sf[g] = (float)sV;
                out_rf[g] = (float)rV;
                if (rs >= 0) atomicAdd(&counts[rs], 1.0f);
            }
            __bf16* xr = &Xs_[row * XS];
#pragma unroll
            for (int i = 0; i < 4; ++i) {
                const int c = 4 * qt + 16 * i;   // bank = (4row'+2qt+8i)%32: 2-way, free
                float4 a = G[i], e = G[4 + i], s = G[8 + i];
                *(bf16x4*)&xr[c] =
                    (bf16x4){(__bf16)a.x, (__bf16)a.y, (__bf16)a.z, (__bf16)a.w};
                *(bf16x4*)&xr[64 + c] =
                    (bf16x4){(__bf16)e.x, (__bf16)e.y, (__bf16)e.z, (__bf16)e.w};
                *(bf16x4*)&xr[128 + c] =
                    (bf16x4){(__bf16)s.x, (__bf16)s.y, (__bf16)s.z, (__bf16)s.w};
            }
        }
        lds_barrier();   // B1: X ready

        // ---- prefetch: gathers for t+stride (idx already in regs), idx for t+2*stride ----
        {
            const int rG = rN, sG = sN;
            const int tn = (t + stride < ntiles) ? (t + stride) : t;
            const int gn = tn * 64 + row;
            const int b  = gn >> 16;
            const int rg = (rG < 0) ? (kBN - 1) : rG + (b << 13);
            const int sg = (sG < 0) ? (kBN - 1) : sG + (b << 13);
            const float4* nrec = (const float4*)nodes + (size_t)rg * 16;
            const float4* ez   = (const float4*)edges + (size_t)gn * 16;
            const float4* nsnd = (const float4*)nodes + (size_t)sg * 16;
#pragma unroll
            for (int i = 0; i < 4; ++i) {
                G[i]     = nrec[qt + 4 * i];
                G[4 + i] = ez  [qt + 4 * i];
                G[8 + i] = nsnd[qt + 4 * i];
            }
            const int t2 = (t + 2 * stride < ntiles) ? (t + 2 * stride) : tn;
            const int g2 = t2 * 64 + row;
            rN = receivers[g2];
            sN = senders[g2];
            rV = rG;   // current-tile idx for next iteration's top
            sV = sG;
        }

        // ---- layer 1: [64x192]@[192x128] -> H, fused per-m to cap VGPRs ----
#pragma unroll
        for (int m = 0; m < 4; ++m) {
            const __bf16* ar = &Xs_[(m * 16 + c16) * XS + q * 8];
            bf16x8 a[6];
#pragma unroll
            for (int kk = 0; kk < 6; ++kk) a[kk] = *(const bf16x8*)(ar + kk * 32);
            f32x4 acc0 = (f32x4){0.f, 0.f, 0.f, 0.f};
            f32x4 acc1 = (f32x4){0.f, 0.f, 0.f, 0.f};
#pragma unroll
            for (int kk = 0; kk < 6; ++kk)
                acc0 = __builtin_amdgcn_mfma_f32_16x16x32_bf16(a[kk], winf[kk][0], acc0, 0, 0, 0);
#pragma unroll
            for (int kk = 0; kk < 6; ++kk)
                acc1 = __builtin_amdgcn_mfma_f32_16x16x32_bf16(a[kk], winf[kk][1], acc1, 0, 0, 0);
#pragma unroll
            for (int r = 0; r < 4; ++r) {
                __bf16* hr = &Hs_[(m * 16 + q * 4 + r) * HS + wave * 32];
                hr[c16]      = (__bf16)fmaxf(acc0[r] + bin0, 0.f);
                hr[16 + c16] = (__bf16)fmaxf(acc1[r] + bin1, 0.f);
            }
        }
        lds_barrier();   // B2: H ready

        // ---- layer 2: [64x128]@[128x64] -> E ----
#pragma unroll
        for (int m = 0; m < 4; ++m) {
            const __bf16* ar = &Hs_[(m * 16 + c16) * HS + q * 8];
            bf16x8 a[4];
#pragma unroll
            for (int kk = 0; kk < 4; ++kk) a[kk] = *(const bf16x8*)(ar + kk * 32);
            f32x4 acc = (f32x4){0.f, 0.f, 0.f, 0.f};
#pragma unroll
            for (int kk = 0; kk < 4; ++kk)
                acc = __builtin_amdgcn_mfma_f32_16x16x32_bf16(a[kk], woutf[kk], acc, 0, 0, 0);
#pragma unroll
            for (int r = 0; r < 4; ++r)
                Es_[(m * 16 + q * 4 + r) * ES + wave * 16 + c16] =
                    (__bf16)fmaxf(acc[r] + bo, 0.f);
        }
        lds_barrier();   // B3: E ready

        // ---- layer 3: [64x64]@[64x64] -> edges_out ----
#pragma unroll
        for (int m = 0; m < 4; ++m) {
            const __bf16* ar = &Es_[(m * 16 + c16) * ES + q * 8];
            bf16x8 a0 = *(const bf16x8*)ar;
            bf16x8 a1 = *(const bf16x8*)(ar + 32);
            f32x4 acc = (f32x4){0.f, 0.f, 0.f, 0.f};
            acc = __builtin_amdgcn_mfma_f32_16x16x32_bf16(a0, wedgef[0], acc, 0, 0, 0);
            acc = __builtin_amdgcn_mfma_f32_16x16x32_bf16(a1, wedgef[1], acc, 0, 0, 0);
#pragma unroll
            for (int r = 0; r < 4; ++r)
                edges_out[(size_t)(g0 + m * 16 + q * 4 + r) * kDE + wave * 16 + c16] =
                    fmaxf(acc[r] + beg, 0.f);
        }

        // ---- scatter e_new -> sums (row per wave, 64 lanes = 256B segment) ----
#pragma unroll
        for (int i = 0; i < 16; ++i) {
            const int rr = i * 4 + wave;
            const int rs = rsS[buf][rr];
            if (rs >= 0) {
                float v = (float)Es_[rr * ES + lane];
                atomicAdd(&sums[(size_t)rs * kDN + lane], v);
            }
        }
        buf ^= 1;
    }
}

// nodes_new = counts>0 ? sums/counts : 0
__global__ __launch_bounds__(256)
void finalize_kernel(const float* __restrict__ sums,
                     const float* __restrict__ counts,
                     float* __restrict__ out)
{
    const int t = blockIdx.x * blockDim.x + threadIdx.x;   // < kBN*kDN/4
    float4 s = ((const float4*)sums)[t];
    const float c = counts[t >> 4];
    float4 o;
    if (c > 0.f) {
        const float inv = 1.f / c;
        o.x = s.x * inv; o.y = s.y * inv; o.z = s.z * inv; o.w = s.w * inv;
    } else {
        o.x = o.y = o.z = o.w = 0.f;
    }
    ((float4*)out)[t] = o;
}

extern "C" void kernel_launch(void* const* d_in, const int* in_sizes, int n_in,
                              void* d_out, int out_size, void* d_ws, size_t ws_size,
                              hipStream_t stream) {
    const float* nodes     = (const float*)d_in[0];
    const float* edges     = (const float*)d_in[1];
    const int*   senders   = (const int*)d_in[2];
    const int*   receivers = (const int*)d_in[3];
    const float* W_in      = (const float*)d_in[4];
    const float* b_in      = (const float*)d_in[5];
    const float* W_out     = (const float*)d_in[6];
    const float* b_out     = (const float*)d_in[7];
    const float* W_edge    = (const float*)d_in[8];
    const float* b_edge    = (const float*)d_in[9];

    float* out    = (float*)d_out;
    float* sums   = (float*)d_ws;
    float* counts = sums + (size_t)kBN * kDN;

    float* edges_out = out + (size_t)kBN * kDN;
    float* out_sf    = edges_out + (size_t)kBE * kDE;
    float* out_rf    = out_sf + kBE;

    hipMemsetAsync(d_ws, 0, (size_t)(kBN * kDN + kBN) * sizeof(float), stream);

    edge_mlp_kernel<<<2048, 256, 0, stream>>>(
        nodes, edges, senders, receivers,
        W_in, b_in, W_out, b_out, W_edge, b_edge,
        edges_out, out_sf, out_rf, sums, counts);

    finalize_kernel<<<kBN * kDN / 4 / 256, 256, 0, stream>>>(sums, counts, out);
}